// Round 4
// baseline (229.146 us; speedup 1.0000x reference)
//
#include <hip/hip_runtime.h>
#include <math.h>

// Problem constants
constexpr int B_ = 4, C_ = 192, N_ = 160, M_ = 160;
constexpr int NM_ = N_ * M_;            // 25600
constexpr float SQRT_C = 13.856406460551018f;   // sqrt(192)
constexpr float SCALE_ = 0.17677669529663687f;  // 1/sqrt(32)

__device__ __forceinline__ float wred_sum(float v) {
    #pragma unroll
    for (int o = 32; o > 0; o >>= 1) v += __shfl_xor(v, o, 64);
    return v;
}
__device__ __forceinline__ float wred_max(float v) {
    #pragma unroll
    for (int o = 32; o > 0; o >>= 1) v = fmaxf(v, __shfl_xor(v, o, 64));
    return v;
}

// K1: fused rn + weight prep. grid 880 x 256
//  blocks [0,400):   rn[b,nm] = sqrt(C)/max(||x[b,:,nm]||,1e-12)  (192-deep loop)
//  blocks [400,592): WfT[hd][t*192+d] = sum_c Wr[d,t*192+c]*Wo[c,hd]; bfb
//  blocks [592,880): WT[mat][c][hd] = g[c]*W[hd*192+c]
__global__ void norm_prep_kernel(const float* __restrict__ x,
                                 const float* __restrict__ Wr, const float* __restrict__ Wo,
                                 const float* __restrict__ bo,
                                 const float* __restrict__ Wq, const float* __restrict__ Wk,
                                 const float* __restrict__ Wv, const float* __restrict__ gq,
                                 const float* __restrict__ gk, const float* __restrict__ gv,
                                 float* __restrict__ rn, float* __restrict__ WfT,
                                 float* __restrict__ bfb, float* __restrict__ WT) {
    int bx = blockIdx.x, tid = threadIdx.x;
    if (bx < 400) {
        int g = bx * 256 + tid;                 // [0,102400)
        int b = g / NM_, nm = g - b * NM_;
        const float* xp = x + (size_t)b * C_ * NM_ + nm;
        float ssq = 0.f;
        #pragma unroll 16
        for (int c = 0; c < C_; c++) { float v = xp[(size_t)c * NM_]; ssq += v * v; }
        rn[g] = SQRT_C / fmaxf(sqrtf(ssq), 1e-12f);
    } else if (bx < 592) {
        int sub = tid >> 7, hd = tid & 127;
        int pair = (bx - 400) * 2 + sub;        // t*192+dch in [0,384)
        int t = pair / 192, dch = pair % 192;
        const float* wr = Wr + dch * 384 + t * 192;
        float acc = 0.f;
        for (int c = 0; c < 192; c++) acc += wr[c] * Wo[c * 128 + hd];
        WfT[hd * 384 + pair] = acc;
        if (hd == 0) {
            float s = 0.f;
            for (int c = 0; c < 192; c++) s += wr[c] * bo[c];
            bfb[pair] = s;
        }
    } else {
        int g = (bx - 592) * 256 + tid;         // < 73728
        int mat = g / 24576, r2 = g % 24576;
        int c = r2 >> 7, hd = r2 & 127;
        const float* W = (mat == 0) ? Wq : ((mat == 1) ? Wk : Wv);
        const float* gg = (mat == 0) ? gq : ((mat == 1) ? gk : gv);
        WT[g] = gg[c] * W[hd * 192 + c];
    }
}

// K2: per (b,c) plane: rowft/Srow (reduce over m), colft/Scol (reduce over n).
// grid 768, block 512
__global__ void rowcol_kernel(const float* __restrict__ x, const float* __restrict__ rn,
                              float* __restrict__ rowft, float* __restrict__ colft,
                              float* __restrict__ Srow, float* __restrict__ Scol) {
    __shared__ float cpart[8][2][160];
    int bc = blockIdx.x;                 // b*192 + c
    int b = bc / C_;
    int tid = threadIdx.x, w = tid >> 6, lane = tid & 63;
    const float* xp = x + (size_t)bc * NM_;
    const float* rp = rn + (size_t)b * NM_;
    int m0 = lane, m1 = lane + 64, m2 = lane + 128;
    bool ok2 = (m2 < M_);
    float cr0 = 0, cr1 = 0, cr2 = 0, cn0 = 0, cn1 = 0, cn2 = 0;
    for (int n = w; n < N_; n += 8) {
        const float* xr = xp + n * M_;
        const float* rr = rp + n * M_;
        float a0 = xr[m0], a1 = xr[m1], a2 = ok2 ? xr[m2] : 0.f;
        float r0 = rr[m0], r1 = rr[m1], r2 = ok2 ? rr[m2] : 0.f;
        float b0 = a0 * r0, b1 = a1 * r1, b2 = a2 * r2;
        cr0 += a0; cr1 += a1; cr2 += a2;
        cn0 += b0; cn1 += b1; cn2 += b2;
        float rs = wred_sum(a0 + a1 + a2);
        float rsn = wred_sum(b0 + b1 + b2);
        if (lane == 0) {
            rowft[bc * N_ + n] = rs * (1.0f / 160.0f);
            Srow[bc * N_ + n] = rsn;
        }
    }
    cpart[w][0][m0] = cr0; cpart[w][0][m1] = cr1; if (ok2) cpart[w][0][m2] = cr2;
    cpart[w][1][m0] = cn0; cpart[w][1][m1] = cn1; if (ok2) cpart[w][1][m2] = cn2;
    __syncthreads();
    if (tid < M_) {
        float sr = 0.f, sn = 0.f;
        #pragma unroll
        for (int ww = 0; ww < 8; ww++) { sr += cpart[ww][0][tid]; sn += cpart[ww][1][tid]; }
        colft[bc * M_ + tid] = sr * (1.0f / 160.0f);
        Scol[bc * M_ + tid] = sn;
    }
}

// K3: Q/K/Vsum projections with fused per-position RMS (g pre-folded into WT).
// grid 480 = (b,t,mat)*20 pos-tiles of 8, block 256
__global__ void proj_kernel(const float* __restrict__ WT,
                            const float* __restrict__ rowft, const float* __restrict__ colft,
                            const float* __restrict__ Srow, const float* __restrict__ Scol,
                            float* __restrict__ Qb, float* __restrict__ Kb, float* __restrict__ Vb) {
    __shared__ float in_s[8 * 200];      // [pos][c], stride 200 (16B-aligned rows)
    __shared__ float sc_s[8];
    int bx = blockIdx.x;
    int pt = bx % 20, rest = bx / 20;
    int mat = rest % 3; int r2 = rest / 3;
    int t = r2 % 2, b = r2 / 2;
    const float* src; float* dst;
    if (mat == 0)      { src = (t == 0) ? rowft : colft; dst = Qb; }
    else if (mat == 1) { src = (t == 0) ? colft : rowft; dst = Kb; }
    else               { src = (t == 0) ? Scol  : Srow;  dst = Vb; }
    const float* Wt = WT + mat * 24576;
    int tid = threadIdx.x;
    for (int idx = tid; idx < 192 * 8; idx += 256) {
        int c = idx >> 3, p = idx & 7;
        in_s[p * 200 + c] = src[(b * C_ + c) * 160 + pt * 8 + p];
    }
    __syncthreads();
    int w = tid >> 6, lane = tid & 63;
    if (mat < 2) {
        #pragma unroll
        for (int qi = 0; qi < 2; qi++) {
            int pos = w * 2 + qi;
            float v0 = in_s[pos * 200 + lane];
            float v1 = in_s[pos * 200 + lane + 64];
            float v2 = in_s[pos * 200 + lane + 128];
            float ssq = wred_sum(v0 * v0 + v1 * v1 + v2 * v2);
            if (lane == 0) sc_s[pos] = SQRT_C / fmaxf(sqrtf(ssq), 1e-12f);
        }
    } else {
        if (tid < 8) sc_s[tid] = 1.0f;
    }
    __syncthreads();
    int hd = tid & 127, pc = tid >> 7, p0 = pc * 4;
    float a0 = 0.f, a1 = 0.f, a2 = 0.f, a3 = 0.f;
    for (int c = 0; c < 192; c += 4) {
        float w0 = Wt[(c + 0) * 128 + hd];
        float w1 = Wt[(c + 1) * 128 + hd];
        float w2 = Wt[(c + 2) * 128 + hd];
        float w3 = Wt[(c + 3) * 128 + hd];
        float4 i0 = *reinterpret_cast<const float4*>(&in_s[(p0 + 0) * 200 + c]);
        float4 i1 = *reinterpret_cast<const float4*>(&in_s[(p0 + 1) * 200 + c]);
        float4 i2 = *reinterpret_cast<const float4*>(&in_s[(p0 + 2) * 200 + c]);
        float4 i3 = *reinterpret_cast<const float4*>(&in_s[(p0 + 3) * 200 + c]);
        a0 += w0 * i0.x + w1 * i0.y + w2 * i0.z + w3 * i0.w;
        a1 += w0 * i1.x + w1 * i1.y + w2 * i1.z + w3 * i1.w;
        a2 += w0 * i2.x + w1 * i2.y + w2 * i2.z + w3 * i2.w;
        a3 += w0 * i3.x + w1 * i3.y + w2 * i3.z + w3 * i3.w;
    }
    int posbase = (b * 2 + t) * 160 + pt * 8 + p0;
    dst[(size_t)(posbase + 0) * 128 + hd] = a0 * sc_s[p0 + 0];
    dst[(size_t)(posbase + 1) * 128 + hd] = a1 * sc_s[p0 + 1];
    dst[(size_t)(posbase + 2) * 128 + hd] = a2 * sc_s[p0 + 2];
    dst[(size_t)(posbase + 3) * 128 + hd] = a3 * sc_s[p0 + 3];
}

// K4: attention. grid 640 = (b,t,h)*20 q-tiles of 8, block 256. Writes AOT[bt][hd][pos].
__global__ void attn_kernel(const float* __restrict__ Qb, const float* __restrict__ Kb,
                            const float* __restrict__ Vb, const float* __restrict__ memkv,
                            float* __restrict__ AOT) {
    __shared__ float k_s[160 * 33];
    __shared__ float v_s[160 * 33];
    __shared__ float q_s[8 * 33];
    __shared__ float e_s[8 * 160];
    __shared__ float mk[128];
    __shared__ float mv[128];
    int bx = blockIdx.x;
    int qt = bx % 20; int r = bx / 20;
    int h = r & 3; r >>= 2;
    int t = r & 1; int b = r >> 1;
    int tid = threadIdx.x, w = tid >> 6, lane = tid & 63;
    int btbase = ((b * 2 + t) * 160) * 128 + h * 32;
    for (int idx = tid; idx < 160 * 32; idx += 256) {
        int kk = idx >> 5, d = idx & 31;
        k_s[kk * 33 + d] = Kb[btbase + kk * 128 + d];
        v_s[kk * 33 + d] = Vb[btbase + kk * 128 + d];
    }
    { int q = tid >> 5, d = tid & 31;
      q_s[q * 33 + d] = Qb[btbase + (qt * 8 + q) * 128 + d]; }
    if (tid < 128) {
        mk[tid] = memkv[h * 128 + tid];
        mv[tid] = memkv[512 + h * 128 + tid];
    }
    __syncthreads();
    float kr0[32], kr1[32], kr2[32];
    #pragma unroll
    for (int d = 0; d < 32; d++) {
        kr0[d] = k_s[lane * 33 + d];
        kr1[d] = k_s[(lane + 64) * 33 + d];
        kr2[d] = (lane < 32) ? k_s[(lane + 128) * 33 + d] : 0.f;
    }
    float p;
    {
        int pj = lane >> 3, qi = pj >> 2, j = pj & 3;
        int db = (lane & 7) * 4;
        p = 0.f;
        #pragma unroll
        for (int dd = 0; dd < 4; dd++)
            p += q_s[(w * 2 + qi) * 33 + db + dd] * mk[j * 32 + db + dd];
        p += __shfl_xor(p, 1, 64); p += __shfl_xor(p, 2, 64); p += __shfl_xor(p, 4, 64);
        p *= SCALE_;
    }
    float sm[2][4];
    #pragma unroll
    for (int j = 0; j < 4; j++) {
        sm[0][j] = __shfl(p, j * 8, 64);
        sm[1][j] = __shfl(p, 32 + j * 8, 64);
    }
    int dpv = lane & 31;
    float Zq[2], accm[2];
    #pragma unroll
    for (int qi = 0; qi < 2; qi++) {
        int qrow = (w * 2 + qi) * 33;
        float s0 = 0, s1 = 0, s2 = 0;
        #pragma unroll
        for (int d = 0; d < 32; d++) {
            float qv = q_s[qrow + d];
            s0 += qv * kr0[d]; s1 += qv * kr1[d]; s2 += qv * kr2[d];
        }
        s0 *= SCALE_; s1 *= SCALE_;
        s2 = (lane < 32) ? s2 * SCALE_ : -1e30f;
        float mx = fmaxf(fmaxf(s0, s1), s2);
        mx = fmaxf(mx, fmaxf(fmaxf(sm[qi][0], sm[qi][1]), fmaxf(sm[qi][2], sm[qi][3])));
        mx = wred_max(mx);
        float e0 = __expf(s0 - mx), e1 = __expf(s1 - mx);
        float e2 = (lane < 32) ? __expf(s2 - mx) : 0.f;
        int eb = (w * 2 + qi) * 160;
        e_s[eb + lane] = e0; e_s[eb + 64 + lane] = e1;
        if (lane < 32) e_s[eb + 128 + lane] = e2;
        float esum = wred_sum(e0 + e1 + e2);
        float em0 = __expf(sm[qi][0] - mx), em1 = __expf(sm[qi][1] - mx);
        float em2 = __expf(sm[qi][2] - mx), em3 = __expf(sm[qi][3] - mx);
        Zq[qi] = (em0 + em1 + em2 + em3) + 160.0f * esum;
        accm[qi] = em0 * mv[dpv] + em1 * mv[32 + dpv] + em2 * mv[64 + dpv] + em3 * mv[96 + dpv];
    }
    int half = lane >> 5, k0 = half * 80;
    int eb0 = (w * 2) * 160, eb1 = (w * 2 + 1) * 160;
    float a0 = 0, a1 = 0;
    for (int kk = 0; kk < 80; kk++) {
        float v = v_s[(k0 + kk) * 33 + dpv];
        a0 += e_s[eb0 + k0 + kk] * v;
        a1 += e_s[eb1 + k0 + kk] * v;
    }
    a0 += __shfl_down(a0, 32, 64);
    a1 += __shfl_down(a1, 32, 64);
    if (lane < 32) {
        int aobase = (b * 2 + t) * 20480 + (h * 32 + lane) * 160 + qt * 8 + w * 2;
        AOT[aobase + 0] = (accm[0] + a0) / Zq[0];
        AOT[aobase + 1] = (accm[1] + a1) / Zq[1];
    }
}

// K5: fused (Wr@Wo) projection + broadcast-add output. grid 768 = (b,dch), block 320.
// threads 0..159: R[p] from AOT[b,t=0]; 160..319: C[m] from AOT[b,t=1]; then tile write.
__global__ void oproj_final_kernel(const float* __restrict__ WfT, const float* __restrict__ bfb,
                                   const float* __restrict__ AOT, float* __restrict__ out) {
    __shared__ float Rl[160];
    __shared__ float Cl[160];
    int bx = blockIdx.x;
    int b = bx / C_, dch = bx % C_;
    int tid = threadIdx.x;
    if (tid < 320) {
        int t = (tid >= 160) ? 1 : 0;
        int p = t ? (tid - 160) : tid;
        const float* ao = AOT + (b * 2 + t) * 20480 + p;
        const float* wf = WfT + t * 192 + dch;
        float acc = 0.f;
        #pragma unroll 8
        for (int hd = 0; hd < 128; hd++)
            acc += wf[hd * 384] * ao[hd * 160];   // wf: uniform (s_load); ao: coalesced
        acc += bfb[t * 192 + dch];
        if (t) Cl[p] = acc; else Rl[p] = acc;
    }
    __syncthreads();
    float* base = out + (size_t)bx * NM_;
    for (int idx = tid; idx < 160 * 40; idx += 320) {
        int n = idx / 40, m4 = idx - n * 40;
        float r = Rl[n];
        float4 v;
        v.x = r + Cl[m4 * 4 + 0];
        v.y = r + Cl[m4 * 4 + 1];
        v.z = r + Cl[m4 * 4 + 2];
        v.w = r + Cl[m4 * 4 + 3];
        *reinterpret_cast<float4*>(base + n * 160 + m4 * 4) = v;
    }
}

extern "C" void kernel_launch(void* const* d_in, const int* in_sizes, int n_in,
                              void* d_out, int out_size, void* d_ws, size_t ws_size,
                              hipStream_t stream) {
    const float* x    = (const float*)d_in[0];
    const float* gq   = (const float*)d_in[1];
    const float* gk   = (const float*)d_in[2];
    const float* gv   = (const float*)d_in[3];
    const float* Wq   = (const float*)d_in[4];
    const float* Wk   = (const float*)d_in[5];
    const float* Wv   = (const float*)d_in[6];
    const float* mkv  = (const float*)d_in[7];
    const float* Wo   = (const float*)d_in[8];
    const float* bo   = (const float*)d_in[9];
    const float* Wr   = (const float*)d_in[10];
    float* out = (float*)d_out;

    float* ws = (float*)d_ws;
    float* rn    = ws;                  // 102400
    float* rowft = rn    + 102400;      // 122880
    float* colft = rowft + 122880;
    float* Srow  = colft + 122880;
    float* Scol  = Srow  + 122880;
    float* WT    = Scol  + 122880;      // 73728
    float* Qb    = WT    + 73728;       // 163840
    float* Kb    = Qb    + 163840;
    float* Vb    = Kb    + 163840;
    float* AOT   = Vb    + 163840;      // 163840
    float* WfT   = AOT   + 163840;      // 49152
    float* bfb   = WfT   + 49152;       // 384

    norm_prep_kernel<<<880, 256, 0, stream>>>(x, Wr, Wo, bo, Wq, Wk, Wv, gq, gk, gv,
                                              rn, WfT, bfb, WT);
    rowcol_kernel<<<768, 512, 0, stream>>>(x, rn, rowft, colft, Srow, Scol);
    proj_kernel<<<480, 256, 0, stream>>>(WT, rowft, colft, Srow, Scol, Qb, Kb, Vb);
    attn_kernel<<<640, 256, 0, stream>>>(Qb, Kb, Vb, mkv, AOT);
    oproj_final_kernel<<<768, 320, 0, stream>>>(WfT, bfb, AOT, out);
}